// Round 1
// baseline (403.441 us; speedup 1.0000x reference)
//
#include <hip/hip_runtime.h>
#include <cfloat>

#define TT 16
#define KK 512
#define DD 128
#define BT 64      // b-tile per workgroup
#define KC 64      // k-chunk staged in LDS
#define STR 132    // LDS row stride in floats: mult of 4 (float4 align), ==4 mod 32 banks
#define N0 16777216  // 8192*16*128 (z_q_st)
#define N1 131072    // 8192*16     (tokens)

// numpy pairwise-sum (n<=128 path: 8 strided accumulators + tree combine) of x^2
__device__ __forceinline__ float np_sum128_sq(const float* __restrict__ row) {
  float r[8];
#pragma unroll
  for (int j = 0; j < 8; ++j) r[j] = __fmul_rn(row[j], row[j]);
  for (int i = 8; i < 128; i += 8) {
#pragma unroll
    for (int j = 0; j < 8; ++j) r[j] = __fadd_rn(r[j], __fmul_rn(row[i + j], row[i + j]));
  }
  return __fadd_rn(__fadd_rn(__fadd_rn(r[0], r[1]), __fadd_rn(r[2], r[3])),
                   __fadd_rn(__fadd_rn(r[4], r[5]), __fadd_rn(r[6], r[7])));
}

__global__ __launch_bounds__(256, 2) void vq_main(
    const float* __restrict__ z_e, const float* __restrict__ cb,
    float* __restrict__ out, float* __restrict__ loss_acc, int* __restrict__ used) {
  __shared__ alignas(16) float z_s[BT * STR];
  __shared__ alignas(16) float c_s[KC * STR];
  __shared__ float A_s[BT];
  __shared__ float q_s[KC];
  __shared__ float redv[BT][16];
  __shared__ int   redi[BT][16];
  __shared__ int   tok_s[BT];

  const int tid = threadIdx.x;
  const int t  = blockIdx.y;
  const int b0 = blockIdx.x * BT;
  const int kg = tid & 15;   // k-group: handles k = kg + 16*j
  const int bg = tid >> 4;   // b-group: handles b = bg + 16*i

  // ---- stage z tile (64 rows x 128 floats), coalesced float4 ----
#pragma unroll
  for (int it = 0; it < 8; ++it) {
    int idx = tid + it * 256;          // float4 index within tile
    int r = idx >> 5, c = idx & 31;
    float4 v = *(const float4*)(z_e + (size_t)(b0 + r) * (TT * DD) + t * DD + c * 4);
    *(float4*)(z_s + r * STR + c * 4) = v;
  }
  __syncthreads();
  if (tid < BT) A_s[tid] = np_sum128_sq(z_s + tid * STR);   // ||z||^2, np order

  float bestv[4];
  int   bestk[4];
#pragma unroll
  for (int i = 0; i < 4; ++i) { bestv[i] = FLT_MAX; bestk[i] = 0; }

  for (int ch = 0; ch < KK / KC; ++ch) {
    const int kbase = ch * KC;
    __syncthreads();  // protect c_s reuse (and A_s visibility on first iter)
#pragma unroll
    for (int it = 0; it < 8; ++it) {
      int idx = tid + it * 256;
      int r = idx >> 5, c = idx & 31;
      float4 v = *(const float4*)(cb + (size_t)t * (KK * DD) + (size_t)(kbase + r) * DD + c * 4);
      *(float4*)(c_s + r * STR + c * 4) = v;
    }
    __syncthreads();
    if (tid < KC) q_s[tid] = np_sum128_sq(c_s + tid * STR);  // ||c||^2, np order
    __syncthreads();

    float acc[4][4];
#pragma unroll
    for (int i = 0; i < 4; ++i)
#pragma unroll
      for (int j = 0; j < 4; ++j) acc[i][j] = 0.0f;

#pragma unroll 4
    for (int d4 = 0; d4 < 32; ++d4) {
      float4 a[4], c[4];
#pragma unroll
      for (int i = 0; i < 4; ++i)
        a[i] = *(const float4*)(z_s + (bg + 16 * i) * STR + d4 * 4);
#pragma unroll
      for (int j = 0; j < 4; ++j)
        c[j] = *(const float4*)(c_s + (kg + 16 * j) * STR + d4 * 4);
#pragma unroll
      for (int i = 0; i < 4; ++i)
#pragma unroll
        for (int j = 0; j < 4; ++j) {
          float s = acc[i][j];
          s = __builtin_fmaf(a[i].x, c[j].x, s);
          s = __builtin_fmaf(a[i].y, c[j].y, s);
          s = __builtin_fmaf(a[i].z, c[j].z, s);
          s = __builtin_fmaf(a[i].w, c[j].w, s);
          acc[i][j] = s;
        }
    }

    // distances d = (A - 2p) + q, reference rounding; running lexicographic min
#pragma unroll
    for (int i = 0; i < 4; ++i) {
      float Ai = A_s[bg + 16 * i];
#pragma unroll
      for (int j = 0; j < 4; ++j) {
        int k = kbase + kg + 16 * j;
        float dist = __fadd_rn(__fsub_rn(Ai, __fmul_rn(2.0f, acc[i][j])), q_s[kg + 16 * j]);
        if (dist < bestv[i] || (dist == bestv[i] && k < bestk[i])) { bestv[i] = dist; bestk[i] = k; }
      }
    }
  }

  // ---- cross-thread argmin reduction per b ----
  __syncthreads();
#pragma unroll
  for (int i = 0; i < 4; ++i) {
    redv[bg + 16 * i][kg] = bestv[i];
    redi[bg + 16 * i][kg] = bestk[i];
  }
  __syncthreads();
  if (tid < BT) {
    float bv = redv[tid][0]; int bk = redi[tid][0];
#pragma unroll
    for (int g = 1; g < 16; ++g) {
      float v = redv[tid][g]; int k = redi[tid][g];
      if (v < bv || (v == bv && k < bk)) { bv = v; bk = k; }
    }
    tok_s[tid] = bk;
    out[(size_t)N0 + (size_t)(b0 + tid) * TT + t] = (float)bk;  // tokens as float
    atomicOr(&used[t * KK + bk], 1);
  }
  __syncthreads();

  // ---- epilogue: z_q_st = z + (c - z), loss partial ----
  float lsum = 0.0f;
#pragma unroll
  for (int it = 0; it < 8; ++it) {
    int idx = tid + it * 256;
    int r = idx >> 5, c = idx & 31;
    int k = tok_s[r];
    float4 cv = *(const float4*)(cb + (size_t)t * (KK * DD) + (size_t)k * DD + c * 4);
    float4 zv = *(const float4*)(z_s + r * STR + c * 4);
    float4 o;
    o.x = __fadd_rn(zv.x, __fsub_rn(cv.x, zv.x));
    o.y = __fadd_rn(zv.y, __fsub_rn(cv.y, zv.y));
    o.z = __fadd_rn(zv.z, __fsub_rn(cv.z, zv.z));
    o.w = __fadd_rn(zv.w, __fsub_rn(cv.w, zv.w));
    float dx = zv.x - cv.x, dy = zv.y - cv.y, dz = zv.z - cv.z, dw = zv.w - cv.w;
    lsum += dx * dx;
    lsum += dy * dy;
    lsum += dz * dz;
    lsum += dw * dw;
    *(float4*)(out + (size_t)(b0 + r) * (TT * DD) + t * DD + c * 4) = o;
  }
#pragma unroll
  for (int off = 32; off > 0; off >>= 1) lsum += __shfl_down(lsum, off, 64);
  if ((tid & 63) == 0) atomicAdd(loss_acc, lsum);
}

__global__ void vq_final(const float* __restrict__ loss_acc, const int* __restrict__ used,
                         float* __restrict__ out) {
  __shared__ int part[4];
  int tid = threadIdx.x;
  int c = 0;
  for (int i = tid; i < TT * KK; i += 256) c += used[i];
#pragma unroll
  for (int off = 32; off > 0; off >>= 1) c += __shfl_down(c, off, 64);
  if ((tid & 63) == 0) part[tid >> 6] = c;
  __syncthreads();
  if (tid == 0) {
    int tot = part[0] + part[1] + part[2] + part[3];
    out[(size_t)N0 + N1]     = 0.25f * loss_acc[0] / 16777216.0f;  // BETA * mean
    out[(size_t)N0 + N1 + 1] = (float)tot / 8192.0f;               // utilization
  }
}

extern "C" void kernel_launch(void* const* d_in, const int* in_sizes, int n_in,
                              void* d_out, int out_size, void* d_ws, size_t ws_size,
                              hipStream_t stream) {
  const float* z_e = (const float*)d_in[0];
  const float* cb  = (const float*)d_in[1];
  float* out = (float*)d_out;
  float* loss_acc = (float*)d_ws;
  int*   used     = (int*)((char*)d_ws + 64);
  hipMemsetAsync(d_ws, 0, 64 + TT * KK * sizeof(int), stream);
  vq_main<<<dim3(8192 / BT, TT), 256, 0, stream>>>(z_e, cb, out, loss_acc, used);
  vq_final<<<1, 256, 0, stream>>>(loss_acc, used, out);
}